// Round 3
// baseline (2818.580 us; speedup 1.0000x reference)
//
#include <hip/hip_runtime.h>

// AF-LSTM on MI355X. Sizes fixed: V=32000, D=H=512, B=64, T=256, A=4, 4H=2048.
// ROUND-2 FINDING: all float tensors are FLOAT32 (reference uses jnp.float32;
// the "(bf16" in the test label is hard-coded template text; threshold ==
// absmax_ref/50 exactly => pure f32 2% threshold). Reading f32 as bf16 made
// ~2^-8 of elements NaN-patterned -> NaN everywhere. x,s are int32.
// d_out is FLOAT32 [64,512].
//
// Strategy: bf16 MFMA for all GEMMs (no fp32 MFMA on CDNA4), converting f32
// operands to bf16 during LDS staging; f32 accumulate; all small kernels f32.

typedef __bf16 bf16x8 __attribute__((ext_vector_type(8)));
typedef float f32x4 __attribute__((ext_vector_type(4)));

#define B_ 64
#define T_ 256
#define D_ 512
#define H4 2048

__device__ __forceinline__ unsigned short f2bf(float f) {
    unsigned u = __float_as_uint(f);
    u += 0x7fffu + ((u >> 16) & 1u);   // round-to-nearest-even
    return (unsigned short)(u >> 16);
}
__device__ __forceinline__ float bf2f(unsigned short x) {
    return __uint_as_float(((unsigned)x) << 16);
}
__device__ __forceinline__ float sigmoidf_(float x) {
    return 1.f / (1.f + expf(-x));
}

// ---------------------------------------------------------------------------
// C = A @ B^T GEMM, bf16 MFMA 16x16x32, 64x64 block tile, 4 waves.
// A rows [M][K]: f32 (a_f32=1, optional gather) or bf16 (a_f32=0, optional
// per-batch stride). B rows [N][K]: f32 Bmat, OR circulant from f32 circ_src:
// B[n][k] = circ_src[bz*512 + ((k-n)&511)].
// Epilogue: optional f32 bias[col], optional tanh, store bf16 or f32.
// grid = (N/64, M/64, batch), block = 256.
// ---------------------------------------------------------------------------
__global__ __launch_bounds__(256)
void gemm_bt(const void* __restrict__ Abase, int a_f32,
             const int* __restrict__ gather_idx,
             const float* __restrict__ Bmat,
             const float* __restrict__ circ_src,
             const float* __restrict__ bias,
             unsigned short* __restrict__ outb,
             float* __restrict__ outf,
             int N, int K,
             long A_bstride, long out_bstride,
             int act)
{
    __shared__ __align__(16) unsigned short Asm[64 * 40];  // +8 pad: only 2-way LDS aliasing
    __shared__ __align__(16) unsigned short Bsm[64 * 40];

    const int bz = blockIdx.z;
    const int tile_n = blockIdx.x * 64;
    const int tile_m = blockIdx.y * 64;
    const int tid = threadIdx.x;
    const int lane = tid & 63;
    const int w = tid >> 6;
    const int wm = (w >> 1) * 32;
    const int wn = (w & 1) * 32;

    const int srow = tid >> 2;        // staging row 0..63
    const int skc = (tid & 3) * 8;    // staging k offset 0,8,16,24

    // A-row base pointer
    const float* arow_f = nullptr;
    const unsigned short* arow_h = nullptr;
    if (a_f32) {
        const float* Af = (const float*)Abase;
        if (gather_idx) arow_f = Af + (long)gather_idx[tile_m + srow] * K;
        else            arow_f = Af + (long)bz * A_bstride + (long)(tile_m + srow) * K;
    } else {
        arow_h = (const unsigned short*)Abase + (long)bz * A_bstride + (long)(tile_m + srow) * K;
    }
    const float* brow = nullptr;
    const float* csrc = nullptr;
    if (circ_src) csrc = circ_src + bz * 512;
    else brow = Bmat + (long)(tile_n + srow) * K;

    f32x4 zero4 = {0.f, 0.f, 0.f, 0.f};
    f32x4 acc00 = zero4, acc01 = zero4, acc10 = zero4, acc11 = zero4;

    const int fr = lane & 15;          // m / n index within 16
    const int fq = (lane >> 4) * 8;    // k offset within 32-chunk

    for (int kc = 0; kc < K; kc += 32) {
        __syncthreads();
        // ---- stage A tile (convert f32->bf16 if needed) ----
        if (a_f32) {
            float4 u0 = *(const float4*)(arow_f + kc + skc);
            float4 u1 = *(const float4*)(arow_f + kc + skc + 4);
            unsigned short tmp[8] __attribute__((aligned(16)));
            tmp[0] = f2bf(u0.x); tmp[1] = f2bf(u0.y); tmp[2] = f2bf(u0.z); tmp[3] = f2bf(u0.w);
            tmp[4] = f2bf(u1.x); tmp[5] = f2bf(u1.y); tmp[6] = f2bf(u1.z); tmp[7] = f2bf(u1.w);
            *(uint4*)&Asm[srow * 40 + skc] = *(const uint4*)tmp;
        } else {
            *(uint4*)&Asm[srow * 40 + skc] = *(const uint4*)(arow_h + kc + skc);
        }
        // ---- stage B tile ----
        if (csrc) {
            unsigned short tmp[8] __attribute__((aligned(16)));
            int n_abs = tile_n + srow;
            #pragma unroll
            for (int j = 0; j < 8; j++) {
                int k_abs = kc + skc + j;
                tmp[j] = f2bf(csrc[(k_abs - n_abs) & 511]);
            }
            *(uint4*)&Bsm[srow * 40 + skc] = *(const uint4*)tmp;
        } else {
            float4 u0 = *(const float4*)(brow + kc + skc);
            float4 u1 = *(const float4*)(brow + kc + skc + 4);
            unsigned short tmp[8] __attribute__((aligned(16)));
            tmp[0] = f2bf(u0.x); tmp[1] = f2bf(u0.y); tmp[2] = f2bf(u0.z); tmp[3] = f2bf(u0.w);
            tmp[4] = f2bf(u1.x); tmp[5] = f2bf(u1.y); tmp[6] = f2bf(u1.z); tmp[7] = f2bf(u1.w);
            *(uint4*)&Bsm[srow * 40 + skc] = *(const uint4*)tmp;
        }
        __syncthreads();
        bf16x8 a0 = *(const bf16x8*)&Asm[(wm + fr) * 40 + fq];
        bf16x8 a1 = *(const bf16x8*)&Asm[(wm + 16 + fr) * 40 + fq];
        bf16x8 b0 = *(const bf16x8*)&Bsm[(wn + fr) * 40 + fq];
        bf16x8 b1 = *(const bf16x8*)&Bsm[(wn + 16 + fr) * 40 + fq];
        acc00 = __builtin_amdgcn_mfma_f32_16x16x32_bf16(a0, b0, acc00, 0, 0, 0);
        acc01 = __builtin_amdgcn_mfma_f32_16x16x32_bf16(a0, b1, acc01, 0, 0, 0);
        acc10 = __builtin_amdgcn_mfma_f32_16x16x32_bf16(a1, b0, acc10, 0, 0, 0);
        acc11 = __builtin_amdgcn_mfma_f32_16x16x32_bf16(a1, b1, acc11, 0, 0, 0);
    }

    // C/D layout (m89-verified): col = lane&15, row = (lane>>4)*4 + reg
    #pragma unroll
    for (int mi = 0; mi < 2; mi++) {
        #pragma unroll
        for (int ni = 0; ni < 2; ni++) {
            f32x4 acc = (mi == 0) ? (ni == 0 ? acc00 : acc01)
                                  : (ni == 0 ? acc10 : acc11);
            #pragma unroll
            for (int rg = 0; rg < 4; rg++) {
                int row = tile_m + wm + mi * 16 + (lane >> 4) * 4 + rg;
                int col = tile_n + wn + ni * 16 + (lane & 15);
                float v = acc[rg];
                if (bias) v += bias[col];
                if (act == 1) v = tanhf(v);
                long oidx = (long)bz * out_bstride + (long)row * N + col;
                if (outb) outb[oidx] = f2bf(v);
                else outf[oidx] = v;
            }
        }
    }
}

// ---------------------------------------------------------------------------
// f32 -> bf16 bulk convert (for W_hh). n multiple of 4. grid*256*4 >= n.
// ---------------------------------------------------------------------------
__global__ __launch_bounds__(256)
void cvt_f32_bf16(const float* __restrict__ src, unsigned short* __restrict__ dst, int n)
{
    int i = (blockIdx.x * 256 + threadIdx.x) * 4;
    if (i < n) {
        float4 v = *(const float4*)(src + i);
        unsigned short tmp[4] __attribute__((aligned(8)));
        tmp[0] = f2bf(v.x); tmp[1] = f2bf(v.y); tmp[2] = f2bf(v.z); tmp[3] = f2bf(v.w);
        *(ushort2*)(dst + i) = *(const ushort2*)tmp;
        *(ushort2*)(dst + i + 2) = *(const ushort2*)(tmp + 2);
    }
}

// ---------------------------------------------------------------------------
// One LSTM time step. grid = 64 blocks (4 batch-groups x 16 col-slices),
// block = 256 (4 waves; wave w handles gate w over 32 d-columns).
// z = h_{t-1} @ W_hh^T (bf16 MFMA, K=512) + Zx[:,t,:]; gate math; c/h update.
// ---------------------------------------------------------------------------
__global__ __launch_bounds__(256)
void lstm_step(const unsigned short* __restrict__ Whh,   // bf16 [2048][512]
               const unsigned short* __restrict__ Zx,    // bf16 [16384][2048]
               unsigned short* __restrict__ Hs,          // bf16 [64][256][512]
               float* __restrict__ cbuf,
               int t)
{
    __shared__ float zl[4][16][32];
    const int bg = blockIdx.x >> 4;   // batch group (16 rows)
    const int nb = blockIdx.x & 15;   // d-column slice (32 cols)
    const int tid = threadIdx.x;
    const int w = tid >> 6;
    const int lane = tid & 63;

    f32x4 zero4 = {0.f, 0.f, 0.f, 0.f};
    f32x4 acc0 = zero4, acc1 = zero4;

    if (t > 0) {
        const int fr = lane & 15;
        const int fq = (lane >> 4) * 8;
        const unsigned short* hprev = Hs + ((long)(bg * 16 + fr) * T_ + (t - 1)) * D_;
        const int n0 = w * 512 + nb * 32;
        const unsigned short* wrow0 = Whh + (long)(n0 + fr) * D_;
        const unsigned short* wrow1 = Whh + (long)(n0 + 16 + fr) * D_;
        #pragma unroll
        for (int kc = 0; kc < 512; kc += 32) {
            int ko = kc + fq;
            bf16x8 a = *(const bf16x8*)(hprev + ko);
            bf16x8 b0 = *(const bf16x8*)(wrow0 + ko);
            bf16x8 b1 = *(const bf16x8*)(wrow1 + ko);
            acc0 = __builtin_amdgcn_mfma_f32_16x16x32_bf16(a, b0, acc0, 0, 0, 0);
            acc1 = __builtin_amdgcn_mfma_f32_16x16x32_bf16(a, b1, acc1, 0, 0, 0);
        }
    }
    {
        const int q4 = (lane >> 4) * 4;
        const int cl = lane & 15;
        #pragma unroll
        for (int rg = 0; rg < 4; rg++) {
            zl[w][q4 + rg][cl] = acc0[rg];
            zl[w][q4 + rg][16 + cl] = acc1[rg];
        }
    }
    __syncthreads();
    for (int e = tid; e < 512; e += 256) {
        int row = e >> 5;
        int d = e & 31;
        int b = bg * 16 + row;
        int dg = nb * 32 + d;
        long zbase = (long)(b * T_ + t) * H4;
        float zi = zl[0][row][d] + bf2f(Zx[zbase + 0 * 512 + dg]);
        float zf = zl[1][row][d] + bf2f(Zx[zbase + 1 * 512 + dg]);
        float zg = zl[2][row][d] + bf2f(Zx[zbase + 2 * 512 + dg]);
        float zo = zl[3][row][d] + bf2f(Zx[zbase + 3 * 512 + dg]);
        float c_old = (t > 0) ? cbuf[b * D_ + dg] : 0.f;
        float iv = sigmoidf_(zi);
        float fv = sigmoidf_(zf);
        float gv = tanhf(zg);
        float ov = sigmoidf_(zo);
        float c = fv * c_old + iv * gv;
        float h = ov * tanhf(c);
        cbuf[b * D_ + dg] = c;
        Hs[(long)(b * T_ + t) * D_ + dg] = f2bf(h);
    }
}

// ---------------------------------------------------------------------------
// Aspect: per-feature mean/var over (B*A)=256 samples, then
// s_norm[b,d] = sum_a (emb - mu) * rsqrt(var + eps). grid=8, block=64. All f32.
// ---------------------------------------------------------------------------
__global__ __launch_bounds__(64)
void aspect_norm(const int* __restrict__ s,
                 const float* __restrict__ embed,
                 float* __restrict__ s_norm)
{
    __shared__ int sidx[256];
    const int tid = threadIdx.x;
    const int d = blockIdx.x * 64 + tid;
    for (int i = tid; i < 256; i += 64) sidx[i] = s[i];
    __syncthreads();
    float sum = 0.f, sq = 0.f;
    for (int i = 0; i < 256; i++) {
        float v = embed[(long)sidx[i] * D_ + d];
        sum += v; sq += v * v;
    }
    float mu = sum * (1.f / 256.f);
    float var = sq * (1.f / 256.f) - mu * mu;
    float rstd = rsqrtf(var + 1e-5f);
    for (int b = 0; b < 64; b++) {
        float acc = 0.f;
        #pragma unroll
        for (int a = 0; a < 4; a++) {
            acc += embed[(long)sidx[b * 4 + a] * D_ + d] - mu;
        }
        s_norm[b * D_ + d] = acc * rstd;
    }
}

// ---------------------------------------------------------------------------
// Softmax over T (axis=1) + r[b,d] = sum_t softmax(apre)[b,t,d]*Hs[b,t,d]
// grid = (2, 64), block = 256; thread owns one (b,d).
// ---------------------------------------------------------------------------
__global__ __launch_bounds__(256)
void attn_r(const float* __restrict__ apre,
            const unsigned short* __restrict__ Hs,
            float* __restrict__ r)
{
    const int b = blockIdx.y;
    const int d = blockIdx.x * 256 + threadIdx.x;
    const float* ap = apre + (long)b * T_ * D_ + d;
    const unsigned short* hp = Hs + (long)b * T_ * D_ + d;
    float mx = ap[0], sm = 1.f;   // seeded from t=0
    for (int t = 1; t < T_; t++) {
        float v = ap[(long)t * D_];
        if (v > mx) { sm = sm * expf(mx - v) + 1.f; mx = v; }
        else sm += expf(v - mx);
    }
    float acc = 0.f;
    for (int t = 0; t < T_; t++) {
        acc += expf(ap[(long)t * D_] - mx) * bf2f(hp[(long)t * D_]);
    }
    r[b * D_ + d] = acc / sm;
}

// ---------------------------------------------------------------------------
// h_star = tanh(r @ w_p^T + Hs[:, -1] @ w_x^T). grid=64 (b), block=256. f32.
// ---------------------------------------------------------------------------
__global__ __launch_bounds__(256)
void hstar_kernel(const float* __restrict__ r,
                  const unsigned short* __restrict__ Hs,
                  const float* __restrict__ w_p,
                  const float* __restrict__ w_x,
                  float* __restrict__ h_star)
{
    __shared__ float rs[512];
    __shared__ float hts[512];
    const int b = blockIdx.x, tid = threadIdx.x;
    const long hlast = ((long)b * T_ + (T_ - 1)) * D_;
    rs[tid] = r[b * D_ + tid];
    rs[tid + 256] = r[b * D_ + 256 + tid];
    hts[tid] = bf2f(Hs[hlast + tid]);
    hts[tid + 256] = bf2f(Hs[hlast + 256 + tid]);
    __syncthreads();
    for (int d = tid; d < 512; d += 256) {
        const float* wp = w_p + (long)d * D_;
        const float* wx = w_x + (long)d * D_;
        float acc = 0.f;
        for (int e = 0; e < 512; e += 4) {
            float4 p1 = *(const float4*)(wp + e);
            float4 p2 = *(const float4*)(wx + e);
            acc += p1.x * rs[e] + p1.y * rs[e + 1] + p1.z * rs[e + 2] + p1.w * rs[e + 3];
            acc += p2.x * hts[e] + p2.y * hts[e + 1] + p2.z * hts[e + 2] + p2.w * hts[e + 3];
        }
        h_star[b * D_ + d] = tanhf(acc);
    }
}

// ---------------------------------------------------------------------------
// out = softmax(h_star @ w_f^T + b_f) over D, f32 out. grid=64, block=256.
// ---------------------------------------------------------------------------
__global__ __launch_bounds__(256)
void out_kernel(const float* __restrict__ h_star,
                const float* __restrict__ w_f,
                const float* __restrict__ b_f,
                float* __restrict__ out)
{
    __shared__ float hs[512];
    __shared__ float lg[512];
    __shared__ float red[8];
    const int b = blockIdx.x, tid = threadIdx.x;
    hs[tid] = h_star[b * D_ + tid];
    hs[tid + 256] = h_star[b * D_ + 256 + tid];
    __syncthreads();
    for (int d = tid; d < 512; d += 256) {
        const float* wr = w_f + (long)d * D_;
        float acc = b_f[d];
        for (int e = 0; e < 512; e += 4) {
            float4 p = *(const float4*)(wr + e);
            acc += p.x * hs[e] + p.y * hs[e + 1] + p.z * hs[e + 2] + p.w * hs[e + 3];
        }
        lg[d] = acc;
    }
    __syncthreads();
    float m0 = fmaxf(lg[tid], lg[tid + 256]);
    for (int off = 32; off > 0; off >>= 1) m0 = fmaxf(m0, __shfl_down(m0, off, 64));
    if ((tid & 63) == 0) red[tid >> 6] = m0;
    __syncthreads();
    float bmax = fmaxf(fmaxf(red[0], red[1]), fmaxf(red[2], red[3]));
    float e0 = expf(lg[tid] - bmax);
    float e1 = expf(lg[tid + 256] - bmax);
    float s0 = e0 + e1;
    for (int off = 32; off > 0; off >>= 1) s0 += __shfl_down(s0, off, 64);
    if ((tid & 63) == 0) red[4 + (tid >> 6)] = s0;
    __syncthreads();
    float inv = 1.f / (red[4] + red[5] + red[6] + red[7]);
    out[b * D_ + tid] = e0 * inv;
    out[b * D_ + 256 + tid] = e1 * inv;
}

// ---------------------------------------------------------------------------
extern "C" void kernel_launch(void* const* d_in, const int* in_sizes, int n_in,
                              void* d_out, int out_size, void* d_ws, size_t ws_size,
                              hipStream_t stream)
{
    (void)in_sizes; (void)n_in; (void)out_size; (void)ws_size;

    const int* x = (const int*)d_in[0];
    const int* s = (const int*)d_in[1];
    const float* embed  = (const float*)d_in[2];
    const float* W_ih   = (const float*)d_in[3];
    const float* W_hh   = (const float*)d_in[4];
    const float* b_lstm = (const float*)d_in[5];
    const float* w_y = (const float*)d_in[6];
    const float* w_t = (const float*)d_in[7];
    const float* w_p = (const float*)d_in[8];
    const float* w_x = (const float*)d_in[9];
    const float* w_f = (const float*)d_in[10];
    const float* b_f = (const float*)d_in[11];

    // Workspace (overlaid), peak 86.5 MB:
    //   [0, 64MiB)  phase1: Zx bf16 [16384][2048]
    //               phase2 (Zx dead): apre f32 @0 (32MiB), mbuf bf16 @32MiB,
    //                                 Ybuf bf16 @48MiB
    //   [64MiB, +16MiB)  Hs bf16 [64][256][512]
    //   then Whh_bf (2MiB), cbuf/s_norm/rbuf/hstar f32 (128KiB each)
    char* ws = (char*)d_ws;
    unsigned short* Zx   = (unsigned short*)(ws + 0);
    float*          apre = (float*)(ws + 0);
    unsigned short* mbuf = (unsigned short*)(ws + 33554432);
    unsigned short* Ybuf = (unsigned short*)(ws + 50331648);
    unsigned short* Hs   = (unsigned short*)(ws + 67108864);
    unsigned short* Whh_bf = (unsigned short*)(ws + 83886080);
    float* cbuf   = (float*)(ws + 85983232);
    float* s_norm = (float*)(ws + 86114304);
    float* rbuf   = (float*)(ws + 86245376);
    float* hstar  = (float*)(ws + 86376448);

    // 0) convert W_hh to bf16 (1,048,576 elems, 4/thread)
    cvt_f32_bf16<<<dim3(1024), dim3(256), 0, stream>>>(W_hh, Whh_bf, H4 * D_);

    // 1) aspect normalization (f32)
    aspect_norm<<<dim3(8), dim3(64), 0, stream>>>(s, embed, s_norm);

    // 2) G1: Zx = embed[x] @ W_ih^T + b_lstm  (M=16384, N=2048, K=512; A,B f32)
    gemm_bt<<<dim3(32, 256, 1), dim3(256), 0, stream>>>(
        embed, 1, x, W_ih, nullptr, b_lstm, Zx, nullptr,
        2048, 512, 0L, 0L, 0);

    // 3) recurrence: one launch per step
    for (int t = 0; t < T_; t++) {
        lstm_step<<<dim3(64), dim3(256), 0, stream>>>(Whh_bf, Zx, Hs, cbuf, t);
    }

    // ---- phase 2: Zx dead; region reused for apre/mbuf/Ybuf ----

    // 4) G2: m[b] = Hs[b] @ circ(s_norm[b])^T  (A bf16, B circulant from f32)
    gemm_bt<<<dim3(8, 4, 64), dim3(256), 0, stream>>>(
        Hs, 0, nullptr, nullptr, s_norm, nullptr, mbuf, nullptr,
        512, 512, (long)(T_ * D_), (long)(T_ * D_), 0);

    // 5) G3: Y = tanh(m @ w_y^T)  (A bf16, B f32)
    gemm_bt<<<dim3(8, 256, 1), dim3(256), 0, stream>>>(
        mbuf, 0, nullptr, w_y, nullptr, nullptr, Ybuf, nullptr,
        512, 512, 0L, 0L, 1);

    // 6) G4: apre = Y @ w_t^T  (A bf16, B f32, f32 out)
    gemm_bt<<<dim3(8, 256, 1), dim3(256), 0, stream>>>(
        Ybuf, 0, nullptr, w_t, nullptr, nullptr, nullptr, apre,
        512, 512, 0L, 0L, 0);

    // 7) softmax over T + r reduction
    attn_r<<<dim3(2, 64), dim3(256), 0, stream>>>(apre, Hs, rbuf);

    // 8) h_star = tanh(r @ w_p^T + h_T @ w_x^T)  (all f32)
    hstar_kernel<<<dim3(64), dim3(256), 0, stream>>>(rbuf, Hs, w_p, w_x, hstar);

    // 9) final logits + softmax -> f32 d_out
    out_kernel<<<dim3(64), dim3(256), 0, stream>>>(hstar, w_f, b_f, (float*)d_out);
}

// Round 6
// 2217.227 us; speedup vs baseline: 1.2712x; 1.2712x over previous
//
#include <hip/hip_runtime.h>

// AF-LSTM on MI355X. Sizes fixed: V=32000, D=H=512, B=64, T=256, A=4, 4H=2048.
// All float tensors f32; x,s int32; d_out f32 [64,512].
// R3 passed @2818us (256 lstm_step launches). R4/R5 persistent kernel hung:
// ROOT CAUSE (found R5 post-mortem): Hex exchange chunk sized [2][4][2048]
// dwords but publishers write nb*256+tid up to 4096 dwords per (slot,bg);
// slot1/bg3 overflow clobbered bar[] with bf16 h-pairs (often negative ints)
// -> tid0 spin `bar[bg] < 16t` never exits -> hang. Protocol itself verified
// correct. R6 fix: Hex = [2][4][4096] dwords (128KB), bar at +131072.

typedef __bf16 bf16x8 __attribute__((ext_vector_type(8)));
typedef float f32x4 __attribute__((ext_vector_type(4)));

#define B_ 64
#define T_ 256
#define D_ 512
#define H4 2048

__device__ __forceinline__ unsigned short f2bf(float f) {
    unsigned u = __float_as_uint(f);
    u += 0x7fffu + ((u >> 16) & 1u);   // round-to-nearest-even
    return (unsigned short)(u >> 16);
}
__device__ __forceinline__ float bf2f(unsigned short x) {
    return __uint_as_float(((unsigned)x) << 16);
}
__device__ __forceinline__ float bf2f_lo(unsigned u) { return __uint_as_float(u << 16); }
__device__ __forceinline__ float bf2f_hi(unsigned u) { return __uint_as_float(u & 0xffff0000u); }
__device__ __forceinline__ float sigmoidf_(float x) {
    return 1.f / (1.f + expf(-x));
}

// ---------------------------------------------------------------------------
// C = A @ B^T GEMM, bf16 MFMA 16x16x32, 64x64 block tile, 4 waves.
// (unchanged from the round-3 passing version)
// ---------------------------------------------------------------------------
__global__ __launch_bounds__(256)
void gemm_bt(const void* __restrict__ Abase, int a_f32,
             const int* __restrict__ gather_idx,
             const float* __restrict__ Bmat,
             const float* __restrict__ circ_src,
             const float* __restrict__ bias,
             unsigned short* __restrict__ outb,
             float* __restrict__ outf,
             int N, int K,
             long A_bstride, long out_bstride,
             int act)
{
    __shared__ __align__(16) unsigned short Asm[64 * 40];
    __shared__ __align__(16) unsigned short Bsm[64 * 40];

    const int bz = blockIdx.z;
    const int tile_n = blockIdx.x * 64;
    const int tile_m = blockIdx.y * 64;
    const int tid = threadIdx.x;
    const int lane = tid & 63;
    const int w = tid >> 6;
    const int wm = (w >> 1) * 32;
    const int wn = (w & 1) * 32;

    const int srow = tid >> 2;
    const int skc = (tid & 3) * 8;

    const float* arow_f = nullptr;
    const unsigned short* arow_h = nullptr;
    if (a_f32) {
        const float* Af = (const float*)Abase;
        if (gather_idx) arow_f = Af + (long)gather_idx[tile_m + srow] * K;
        else            arow_f = Af + (long)bz * A_bstride + (long)(tile_m + srow) * K;
    } else {
        arow_h = (const unsigned short*)Abase + (long)bz * A_bstride + (long)(tile_m + srow) * K;
    }
    const float* brow = nullptr;
    const float* csrc = nullptr;
    if (circ_src) csrc = circ_src + bz * 512;
    else brow = Bmat + (long)(tile_n + srow) * K;

    f32x4 zero4 = {0.f, 0.f, 0.f, 0.f};
    f32x4 acc00 = zero4, acc01 = zero4, acc10 = zero4, acc11 = zero4;

    const int fr = lane & 15;
    const int fq = (lane >> 4) * 8;

    for (int kc = 0; kc < K; kc += 32) {
        __syncthreads();
        if (a_f32) {
            float4 u0 = *(const float4*)(arow_f + kc + skc);
            float4 u1 = *(const float4*)(arow_f + kc + skc + 4);
            unsigned short tmp[8] __attribute__((aligned(16)));
            tmp[0] = f2bf(u0.x); tmp[1] = f2bf(u0.y); tmp[2] = f2bf(u0.z); tmp[3] = f2bf(u0.w);
            tmp[4] = f2bf(u1.x); tmp[5] = f2bf(u1.y); tmp[6] = f2bf(u1.z); tmp[7] = f2bf(u1.w);
            *(uint4*)&Asm[srow * 40 + skc] = *(const uint4*)tmp;
        } else {
            *(uint4*)&Asm[srow * 40 + skc] = *(const uint4*)(arow_h + kc + skc);
        }
        if (csrc) {
            unsigned short tmp[8] __attribute__((aligned(16)));
            int n_abs = tile_n + srow;
            #pragma unroll
            for (int j = 0; j < 8; j++) {
                int k_abs = kc + skc + j;
                tmp[j] = f2bf(csrc[(k_abs - n_abs) & 511]);
            }
            *(uint4*)&Bsm[srow * 40 + skc] = *(const uint4*)tmp;
        } else {
            float4 u0 = *(const float4*)(brow + kc + skc);
            float4 u1 = *(const float4*)(brow + kc + skc + 4);
            unsigned short tmp[8] __attribute__((aligned(16)));
            tmp[0] = f2bf(u0.x); tmp[1] = f2bf(u0.y); tmp[2] = f2bf(u0.z); tmp[3] = f2bf(u0.w);
            tmp[4] = f2bf(u1.x); tmp[5] = f2bf(u1.y); tmp[6] = f2bf(u1.z); tmp[7] = f2bf(u1.w);
            *(uint4*)&Bsm[srow * 40 + skc] = *(const uint4*)tmp;
        }
        __syncthreads();
        bf16x8 a0 = *(const bf16x8*)&Asm[(wm + fr) * 40 + fq];
        bf16x8 a1 = *(const bf16x8*)&Asm[(wm + 16 + fr) * 40 + fq];
        bf16x8 b0 = *(const bf16x8*)&Bsm[(wn + fr) * 40 + fq];
        bf16x8 b1 = *(const bf16x8*)&Bsm[(wn + 16 + fr) * 40 + fq];
        acc00 = __builtin_amdgcn_mfma_f32_16x16x32_bf16(a0, b0, acc00, 0, 0, 0);
        acc01 = __builtin_amdgcn_mfma_f32_16x16x32_bf16(a0, b1, acc01, 0, 0, 0);
        acc10 = __builtin_amdgcn_mfma_f32_16x16x32_bf16(a1, b0, acc10, 0, 0, 0);
        acc11 = __builtin_amdgcn_mfma_f32_16x16x32_bf16(a1, b1, acc11, 0, 0, 0);
    }

    #pragma unroll
    for (int mi = 0; mi < 2; mi++) {
        #pragma unroll
        for (int ni = 0; ni < 2; ni++) {
            f32x4 acc = (mi == 0) ? (ni == 0 ? acc00 : acc01)
                                  : (ni == 0 ? acc10 : acc11);
            #pragma unroll
            for (int rg = 0; rg < 4; rg++) {
                int row = tile_m + wm + mi * 16 + (lane >> 4) * 4 + rg;
                int col = tile_n + wn + ni * 16 + (lane & 15);
                float v = acc[rg];
                if (bias) v += bias[col];
                if (act == 1) v = tanhf(v);
                long oidx = (long)bz * out_bstride + (long)row * N + col;
                if (outb) outb[oidx] = f2bf(v);
                else outf[oidx] = v;
            }
        }
    }
}

// ---------------------------------------------------------------------------
// Persistent LSTM recurrence, 64 blocks x 512 threads (8 waves).
// bg = blockIdx>>4 owns batches [bg*16, bg*16+16); nb = blockIdx&15 owns
// cols [nb*32, nb*32+32) of every gate => 128 W_hh rows per block.
// Wave w (0..7): gate g=w>>1, fragment f=w&1 -> B-rows g*512+nb*32+f*16..+16,
// held in REGISTERS as 16 bf16x8 chunks/lane (64 VGPR).
// Per-step: spin on bar[bg] (16 blocks/group), stage h_{t-1} from Hex
// (agent-scope atomics, ping-pong), 16 MFMAs/wave, gate math (c in regs),
// publish h. LDS: hsm 16x520 ushort + zl 4x16x33 f32 = 25KB static.
// Hex chunk per (slot,bg) = 4096 dwords (16 batches x 256 col-pairs) -- the
// R4/R5 bug was sizing this 2048.
// ---------------------------------------------------------------------------
#define WSTRIDE 520
#define HEXCH 4096
#define ZL(g,r,d) zl[((g)*16+(r))*33+(d)]

__global__ __launch_bounds__(512)
void persistent_lstm(const float* __restrict__ Whh,         // f32 [2048][512]
                     const unsigned short* __restrict__ Zx, // bf16 [16384][2048]
                     unsigned short* __restrict__ Hs,       // bf16 [64][256][512]
                     unsigned int* __restrict__ HexU32,     // [2][4][4096] dwords
                     int* __restrict__ bar)                 // [4]
{
    __shared__ __align__(16) unsigned short hsm[16 * WSTRIDE];  // 16,640 B
    __shared__ float zl[4 * 16 * 33];                           //  8,448 B

    const int bg = blockIdx.x >> 4;
    const int nb = blockIdx.x & 15;
    const int tid = threadIdx.x;
    const int w = tid >> 6;        // 0..7
    const int lane = tid & 63;
    const int fr = lane & 15;
    const int fq = (lane >> 4) * 8;
    const int g = w >> 1;          // gate
    const int f = w & 1;           // 16-row fragment within gate's 32 cols

    // ---- one-time: this wave's W_hh fragment rows into registers ----
    bf16x8 wfrag[16];
    {
        const float* wrow = Whh + (long)(g * 512 + nb * 32 + f * 16 + fr) * 512;
        #pragma unroll
        for (int c = 0; c < 16; c++) {
            int k0 = c * 32 + fq;
            float4 u0 = *(const float4*)(wrow + k0);
            float4 u1 = *(const float4*)(wrow + k0 + 4);
            unsigned short tmp[8] __attribute__((aligned(16)));
            tmp[0] = f2bf(u0.x); tmp[1] = f2bf(u0.y); tmp[2] = f2bf(u0.z); tmp[3] = f2bf(u0.w);
            tmp[4] = f2bf(u1.x); tmp[5] = f2bf(u1.y); tmp[6] = f2bf(u1.z); tmp[7] = f2bf(u1.w);
            wfrag[c] = *(const bf16x8*)tmp;
        }
    }

    // gate-math ownership (threads 0..255): row grow, col pair (d0, d0+1)
    const int grow = (tid & 255) >> 4;
    const int d0 = (tid & 15) * 2;
    const int b_own = bg * 16 + grow;
    const int dg = nb * 32 + d0;
    float ca = 0.f, cb = 0.f;      // cell state in registers (threads < 256)

    f32x4 zero4 = {0.f, 0.f, 0.f, 0.f};

    for (int t = 0; t < T_; t++) {
        // Zx gate pre-activations: independent of h -> load early
        unsigned zi_u = 0, zf_u = 0, zg_u = 0, zo_u = 0;
        if (tid < 256) {
            const long zb = ((long)b_own * T_ + t) * H4 + dg;
            zi_u = *(const unsigned*)&Zx[zb + 0 * 512];
            zf_u = *(const unsigned*)&Zx[zb + 1 * 512];
            zg_u = *(const unsigned*)&Zx[zb + 2 * 512];
            zo_u = *(const unsigned*)&Zx[zb + 3 * 512];
        }

        f32x4 acc = zero4;
        if (t > 0) {
            // wait until all 16 blocks of this group published h_{t-1}
            if (tid == 0) {
                const int target = 16 * t;
                while (__hip_atomic_load(&bar[bg], __ATOMIC_ACQUIRE,
                                         __HIP_MEMORY_SCOPE_AGENT) < target)
                    __builtin_amdgcn_s_sleep(2);
            }
            __syncthreads();
            // stage h_{t-1} (16 batches x 512 cols = 4096 dwords) from slot (t-1)&1
            // chunk dword layout (writer nb'=p): p*256 + r*16 + cpl
            //   -> h[bg*16+r][p*32 + cpl*2 .. +1]
            const unsigned int* hexbase = HexU32 + (((t - 1) & 1) * 4 + bg) * HEXCH;
            #pragma unroll
            for (int it = 0; it < 8; it++) {
                int idx = it * 512 + tid;          // 0..4095
                int p = idx >> 8;
                int local = idx & 255;
                int r = local >> 4;
                int cpl = local & 15;
                unsigned int v = __hip_atomic_load(hexbase + idx,
                                                   __ATOMIC_RELAXED, __HIP_MEMORY_SCOPE_AGENT);
                *(unsigned int*)&hsm[r * WSTRIDE + p * 32 + cpl * 2] = v;
            }
            __syncthreads();
            // z_frag = h_{t-1}[16x512] @ Wfrag^T : 16 MFMAs over K=512
            const unsigned short* arow = hsm + fr * WSTRIDE;
            #pragma unroll
            for (int c = 0; c < 16; c++) {
                bf16x8 a = *(const bf16x8*)(arow + c * 32 + fq);
                acc = __builtin_amdgcn_mfma_f32_16x16x32_bf16(a, wfrag[c], acc, 0, 0, 0);
            }
        }
        // scatter z to LDS (C/D: col=lane&15, row=(lane>>4)*4+reg)
        {
            const int q4 = (lane >> 4) * 4;
            const int cl = f * 16 + (lane & 15);
            #pragma unroll
            for (int rg = 0; rg < 4; rg++) {
                ZL(g, q4 + rg, cl) = acc[rg];
            }
        }
        __syncthreads();
        // gate math on threads 0..255 (wave-uniform branch)
        if (tid < 256) {
            float zi0 = ZL(0, grow, d0)     + bf2f_lo(zi_u);
            float zi1 = ZL(0, grow, d0 + 1) + bf2f_hi(zi_u);
            float zf0 = ZL(1, grow, d0)     + bf2f_lo(zf_u);
            float zf1 = ZL(1, grow, d0 + 1) + bf2f_hi(zf_u);
            float zg0 = ZL(2, grow, d0)     + bf2f_lo(zg_u);
            float zg1 = ZL(2, grow, d0 + 1) + bf2f_hi(zg_u);
            float zo0 = ZL(3, grow, d0)     + bf2f_lo(zo_u);
            float zo1 = ZL(3, grow, d0 + 1) + bf2f_hi(zo_u);

            ca = sigmoidf_(zf0) * ca + sigmoidf_(zi0) * tanhf(zg0);
            cb = sigmoidf_(zf1) * cb + sigmoidf_(zi1) * tanhf(zg1);
            float h0 = sigmoidf_(zo0) * tanhf(ca);
            float h1 = sigmoidf_(zo1) * tanhf(cb);

            unsigned hp = (unsigned)f2bf(h0) | ((unsigned)f2bf(h1) << 16);
            // history (plain store; consumed only after kernel completion)
            *(unsigned*)&Hs[((long)b_own * T_ + t) * D_ + dg] = hp;
            // publish to exchange slot t&1 (agent scope); index nb*256+tid < 4096
            __hip_atomic_store(HexU32 + ((t & 1) * 4 + bg) * HEXCH + nb * 256 + (tid & 255),
                               hp, __ATOMIC_RELAXED, __HIP_MEMORY_SCOPE_AGENT);
        }
        __syncthreads();   // vmcnt(0) before barrier -> publishes drained
        if (tid == 0)
            __hip_atomic_fetch_add(&bar[bg], 1, __ATOMIC_RELEASE, __HIP_MEMORY_SCOPE_AGENT);
    }
}

// ---------------------------------------------------------------------------
// Aspect normalization (unchanged)
// ---------------------------------------------------------------------------
__global__ __launch_bounds__(64)
void aspect_norm(const int* __restrict__ s,
                 const float* __restrict__ embed,
                 float* __restrict__ s_norm)
{
    __shared__ int sidx[256];
    const int tid = threadIdx.x;
    const int d = blockIdx.x * 64 + tid;
    for (int i = tid; i < 256; i += 64) sidx[i] = s[i];
    __syncthreads();
    float sum = 0.f, sq = 0.f;
    for (int i = 0; i < 256; i++) {
        float v = embed[(long)sidx[i] * D_ + d];
        sum += v; sq += v * v;
    }
    float mu = sum * (1.f / 256.f);
    float var = sq * (1.f / 256.f) - mu * mu;
    float rstd = rsqrtf(var + 1e-5f);
    for (int b = 0; b < 64; b++) {
        float acc = 0.f;
        #pragma unroll
        for (int a = 0; a < 4; a++) {
            acc += embed[(long)sidx[b * 4 + a] * D_ + d] - mu;
        }
        s_norm[b * D_ + d] = acc * rstd;
    }
}

// ---------------------------------------------------------------------------
// Softmax over T + r reduction (unchanged)
// ---------------------------------------------------------------------------
__global__ __launch_bounds__(256)
void attn_r(const float* __restrict__ apre,
            const unsigned short* __restrict__ Hs,
            float* __restrict__ r)
{
    const int b = blockIdx.y;
    const int d = blockIdx.x * 256 + threadIdx.x;
    const float* ap = apre + (long)b * T_ * D_ + d;
    const unsigned short* hp = Hs + (long)b * T_ * D_ + d;
    float mx = ap[0], sm = 1.f;
    for (int t = 1; t < T_; t++) {
        float v = ap[(long)t * D_];
        if (v > mx) { sm = sm * expf(mx - v) + 1.f; mx = v; }
        else sm += expf(v - mx);
    }
    float acc = 0.f;
    for (int t = 0; t < T_; t++) {
        acc += expf(ap[(long)t * D_] - mx) * bf2f(hp[(long)t * D_]);
    }
    r[b * D_ + d] = acc / sm;
}

// ---------------------------------------------------------------------------
// h_star = tanh(r @ w_p^T + Hs[:, -1] @ w_x^T) (unchanged)
// ---------------------------------------------------------------------------
__global__ __launch_bounds__(256)
void hstar_kernel(const float* __restrict__ r,
                  const unsigned short* __restrict__ Hs,
                  const float* __restrict__ w_p,
                  const float* __restrict__ w_x,
                  float* __restrict__ h_star)
{
    __shared__ float rs[512];
    __shared__ float hts[512];
    const int b = blockIdx.x, tid = threadIdx.x;
    const long hlast = ((long)b * T_ + (T_ - 1)) * D_;
    rs[tid] = r[b * D_ + tid];
    rs[tid + 256] = r[b * D_ + 256 + tid];
    hts[tid] = bf2f(Hs[hlast + tid]);
    hts[tid + 256] = bf2f(Hs[hlast + 256 + tid]);
    __syncthreads();
    for (int d = tid; d < 512; d += 256) {
        const float* wp = w_p + (long)d * D_;
        const float* wx = w_x + (long)d * D_;
        float acc = 0.f;
        for (int e = 0; e < 512; e += 4) {
            float4 p1 = *(const float4*)(wp + e);
            float4 p2 = *(const float4*)(wx + e);
            acc += p1.x * rs[e] + p1.y * rs[e + 1] + p1.z * rs[e + 2] + p1.w * rs[e + 3];
            acc += p2.x * hts[e] + p2.y * hts[e + 1] + p2.z * hts[e + 2] + p2.w * hts[e + 3];
        }
        h_star[b * D_ + d] = tanhf(acc);
    }
}

// ---------------------------------------------------------------------------
// out = softmax(h_star @ w_f^T + b_f) (unchanged)
// ---------------------------------------------------------------------------
__global__ __launch_bounds__(256)
void out_kernel(const float* __restrict__ h_star,
                const float* __restrict__ w_f,
                const float* __restrict__ b_f,
                float* __restrict__ out)
{
    __shared__ float hs[512];
    __shared__ float lg[512];
    __shared__ float red[8];
    const int b = blockIdx.x, tid = threadIdx.x;
    hs[tid] = h_star[b * D_ + tid];
    hs[tid + 256] = h_star[b * D_ + 256 + tid];
    __syncthreads();
    for (int d = tid; d < 512; d += 256) {
        const float* wr = w_f + (long)d * D_;
        float acc = b_f[d];
        for (int e = 0; e < 512; e += 4) {
            float4 p = *(const float4*)(wr + e);
            acc += p.x * hs[e] + p.y * hs[e + 1] + p.z * hs[e + 2] + p.w * hs[e + 3];
        }
        lg[d] = acc;
    }
    __syncthreads();
    float m0 = fmaxf(lg[tid], lg[tid + 256]);
    for (int off = 32; off > 0; off >>= 1) m0 = fmaxf(m0, __shfl_down(m0, off, 64));
    if ((tid & 63) == 0) red[tid >> 6] = m0;
    __syncthreads();
    float bmax = fmaxf(fmaxf(red[0], red[1]), fmaxf(red[2], red[3]));
    float e0 = expf(lg[tid] - bmax);
    float e1 = expf(lg[tid + 256] - bmax);
    float s0 = e0 + e1;
    for (int off = 32; off > 0; off >>= 1) s0 += __shfl_down(s0, off, 64);
    if ((tid & 63) == 0) red[4 + (tid >> 6)] = s0;
    __syncthreads();
    float inv = 1.f / (red[4] + red[5] + red[6] + red[7]);
    out[b * D_ + tid] = e0 * inv;
    out[b * D_ + 256 + tid] = e1 * inv;
}

// ---------------------------------------------------------------------------
extern "C" void kernel_launch(void* const* d_in, const int* in_sizes, int n_in,
                              void* d_out, int out_size, void* d_ws, size_t ws_size,
                              hipStream_t stream)
{
    (void)in_sizes; (void)n_in; (void)out_size; (void)ws_size;

    const int* x = (const int*)d_in[0];
    const int* s = (const int*)d_in[1];
    const float* embed  = (const float*)d_in[2];
    const float* W_ih   = (const float*)d_in[3];
    const float* W_hh   = (const float*)d_in[4];
    const float* b_lstm = (const float*)d_in[5];
    const float* w_y = (const float*)d_in[6];
    const float* w_t = (const float*)d_in[7];
    const float* w_p = (const float*)d_in[8];
    const float* w_x = (const float*)d_in[9];
    const float* w_f = (const float*)d_in[10];
    const float* b_f = (const float*)d_in[11];

    // Workspace (overlaid), peak ~86.5 MB:
    //   [0,64MiB)   phase1: Zx bf16 [16384][2048]
    //               phase2: apre f32 @0, mbuf bf16 @32MiB, Ybuf bf16 @48MiB
    //   [64MiB,+16MiB) Hs bf16
    //   @83886080: Hex [2][4][4096] dwords = 131072 B (R6: was 65536 -> OOB)
    //   @84017152: bar (16B)
    //   @86114304: s_norm, @86245376: rbuf, @86376448: hstar
    char* ws = (char*)d_ws;
    unsigned short* Zx   = (unsigned short*)(ws + 0);
    float*          apre = (float*)(ws + 0);
    unsigned short* mbuf = (unsigned short*)(ws + 33554432);
    unsigned short* Ybuf = (unsigned short*)(ws + 50331648);
    unsigned short* Hs   = (unsigned short*)(ws + 67108864);
    unsigned int*   Hex  = (unsigned int*)(ws + 83886080);
    int*            bar  = (int*)(ws + 84017152);
    float* s_norm = (float*)(ws + 86114304);
    float* rbuf   = (float*)(ws + 86245376);
    float* hstar  = (float*)(ws + 86376448);

    // 0) zero the group barrier counters (ws is re-poisoned before every launch)
    hipMemsetAsync(bar, 0, 16, stream);

    // 1) aspect normalization
    aspect_norm<<<dim3(8), dim3(64), 0, stream>>>(s, embed, s_norm);

    // 2) G1: Zx = embed[x] @ W_ih^T + b_lstm  (M=16384, N=2048, K=512)
    gemm_bt<<<dim3(32, 256, 1), dim3(256), 0, stream>>>(
        embed, 1, x, W_ih, nullptr, b_lstm, Zx, nullptr,
        2048, 512, 0L, 0L, 0);

    // 3) recurrence: ONE persistent kernel, 64 blocks x 512 threads
    persistent_lstm<<<dim3(64), dim3(512), 0, stream>>>(
        W_hh, Zx, Hs, Hex, bar);

    // ---- phase 2: Zx dead; region reused for apre/mbuf/Ybuf ----

    // 4) G2: m[b] = Hs[b] @ circ(s_norm[b])^T
    gemm_bt<<<dim3(8, 4, 64), dim3(256), 0, stream>>>(
        Hs, 0, nullptr, nullptr, s_norm, nullptr, mbuf, nullptr,
        512, 512, (long)(T_ * D_), (long)(T_ * D_), 0);

    // 5) G3: Y = tanh(m @ w_y^T)
    gemm_bt<<<dim3(8, 256, 1), dim3(256), 0, stream>>>(
        mbuf, 0, nullptr, w_y, nullptr, nullptr, Ybuf, nullptr,
        512, 512, 0L, 0L, 1);

    // 6) G4: apre = Y @ w_t^T
    gemm_bt<<<dim3(8, 256, 1), dim3(256), 0, stream>>>(
        Ybuf, 0, nullptr, w_t, nullptr, nullptr, nullptr, apre,
        512, 512, 0L, 0L, 0);

    // 7) softmax over T + r reduction
    attn_r<<<dim3(2, 64), dim3(256), 0, stream>>>(apre, Hs, rbuf);

    // 8) h_star
    hstar_kernel<<<dim3(64), dim3(256), 0, stream>>>(rbuf, Hs, w_p, w_x, hstar);

    // 9) final logits + softmax
    out_kernel<<<dim3(64), dim3(256), 0, stream>>>(hstar, w_f, b_f, (float*)d_out);
}

// Round 7
// 1927.455 us; speedup vs baseline: 1.4623x; 1.1503x over previous
//
#include <hip/hip_runtime.h>

// AF-LSTM on MI355X. Sizes fixed: V=32000, D=H=512, B=64, T=256, A=4, 4H=2048.
// All float tensors f32; x,s int32; d_out f32 [64,512].
// R6 passed @2217us; persistent_lstm = 1590us with MfmaUtil 0.85%, Occ 6% =>
// pure sync latency: bar[4] shares ONE cacheline -> 64 device-scope RMWs/step
// serialize (~5.5us/step). R7: no central counter. Per-publisher flags padded
// to 256B, release-store by publisher, acquire-poll by consumers (ballot over
// 16 lanes). Monotonic epochs per slot (consumer at t needs flag >= t).

typedef __bf16 bf16x8 __attribute__((ext_vector_type(8)));
typedef float f32x4 __attribute__((ext_vector_type(4)));

#define B_ 64
#define T_ 256
#define D_ 512
#define H4 2048

__device__ __forceinline__ unsigned short f2bf(float f) {
    unsigned u = __float_as_uint(f);
    u += 0x7fffu + ((u >> 16) & 1u);   // round-to-nearest-even
    return (unsigned short)(u >> 16);
}
__device__ __forceinline__ float bf2f(unsigned short x) {
    return __uint_as_float(((unsigned)x) << 16);
}
__device__ __forceinline__ float bf2f_lo(unsigned u) { return __uint_as_float(u << 16); }
__device__ __forceinline__ float bf2f_hi(unsigned u) { return __uint_as_float(u & 0xffff0000u); }
__device__ __forceinline__ float sigmoidf_(float x) {
    return 1.f / (1.f + expf(-x));
}

// ---------------------------------------------------------------------------
// C = A @ B^T GEMM, bf16 MFMA 16x16x32, 64x64 block tile, 4 waves.
// (unchanged from the round-3 passing version)
// ---------------------------------------------------------------------------
__global__ __launch_bounds__(256)
void gemm_bt(const void* __restrict__ Abase, int a_f32,
             const int* __restrict__ gather_idx,
             const float* __restrict__ Bmat,
             const float* __restrict__ circ_src,
             const float* __restrict__ bias,
             unsigned short* __restrict__ outb,
             float* __restrict__ outf,
             int N, int K,
             long A_bstride, long out_bstride,
             int act)
{
    __shared__ __align__(16) unsigned short Asm[64 * 40];
    __shared__ __align__(16) unsigned short Bsm[64 * 40];

    const int bz = blockIdx.z;
    const int tile_n = blockIdx.x * 64;
    const int tile_m = blockIdx.y * 64;
    const int tid = threadIdx.x;
    const int lane = tid & 63;
    const int w = tid >> 6;
    const int wm = (w >> 1) * 32;
    const int wn = (w & 1) * 32;

    const int srow = tid >> 2;
    const int skc = (tid & 3) * 8;

    const float* arow_f = nullptr;
    const unsigned short* arow_h = nullptr;
    if (a_f32) {
        const float* Af = (const float*)Abase;
        if (gather_idx) arow_f = Af + (long)gather_idx[tile_m + srow] * K;
        else            arow_f = Af + (long)bz * A_bstride + (long)(tile_m + srow) * K;
    } else {
        arow_h = (const unsigned short*)Abase + (long)bz * A_bstride + (long)(tile_m + srow) * K;
    }
    const float* brow = nullptr;
    const float* csrc = nullptr;
    if (circ_src) csrc = circ_src + bz * 512;
    else brow = Bmat + (long)(tile_n + srow) * K;

    f32x4 zero4 = {0.f, 0.f, 0.f, 0.f};
    f32x4 acc00 = zero4, acc01 = zero4, acc10 = zero4, acc11 = zero4;

    const int fr = lane & 15;
    const int fq = (lane >> 4) * 8;

    for (int kc = 0; kc < K; kc += 32) {
        __syncthreads();
        if (a_f32) {
            float4 u0 = *(const float4*)(arow_f + kc + skc);
            float4 u1 = *(const float4*)(arow_f + kc + skc + 4);
            unsigned short tmp[8] __attribute__((aligned(16)));
            tmp[0] = f2bf(u0.x); tmp[1] = f2bf(u0.y); tmp[2] = f2bf(u0.z); tmp[3] = f2bf(u0.w);
            tmp[4] = f2bf(u1.x); tmp[5] = f2bf(u1.y); tmp[6] = f2bf(u1.z); tmp[7] = f2bf(u1.w);
            *(uint4*)&Asm[srow * 40 + skc] = *(const uint4*)tmp;
        } else {
            *(uint4*)&Asm[srow * 40 + skc] = *(const uint4*)(arow_h + kc + skc);
        }
        if (csrc) {
            unsigned short tmp[8] __attribute__((aligned(16)));
            int n_abs = tile_n + srow;
            #pragma unroll
            for (int j = 0; j < 8; j++) {
                int k_abs = kc + skc + j;
                tmp[j] = f2bf(csrc[(k_abs - n_abs) & 511]);
            }
            *(uint4*)&Bsm[srow * 40 + skc] = *(const uint4*)tmp;
        } else {
            float4 u0 = *(const float4*)(brow + kc + skc);
            float4 u1 = *(const float4*)(brow + kc + skc + 4);
            unsigned short tmp[8] __attribute__((aligned(16)));
            tmp[0] = f2bf(u0.x); tmp[1] = f2bf(u0.y); tmp[2] = f2bf(u0.z); tmp[3] = f2bf(u0.w);
            tmp[4] = f2bf(u1.x); tmp[5] = f2bf(u1.y); tmp[6] = f2bf(u1.z); tmp[7] = f2bf(u1.w);
            *(uint4*)&Bsm[srow * 40 + skc] = *(const uint4*)tmp;
        }
        __syncthreads();
        bf16x8 a0 = *(const bf16x8*)&Asm[(wm + fr) * 40 + fq];
        bf16x8 a1 = *(const bf16x8*)&Asm[(wm + 16 + fr) * 40 + fq];
        bf16x8 b0 = *(const bf16x8*)&Bsm[(wn + fr) * 40 + fq];
        bf16x8 b1 = *(const bf16x8*)&Bsm[(wn + 16 + fr) * 40 + fq];
        acc00 = __builtin_amdgcn_mfma_f32_16x16x32_bf16(a0, b0, acc00, 0, 0, 0);
        acc01 = __builtin_amdgcn_mfma_f32_16x16x32_bf16(a0, b1, acc01, 0, 0, 0);
        acc10 = __builtin_amdgcn_mfma_f32_16x16x32_bf16(a1, b0, acc10, 0, 0, 0);
        acc11 = __builtin_amdgcn_mfma_f32_16x16x32_bf16(a1, b1, acc11, 0, 0, 0);
    }

    #pragma unroll
    for (int mi = 0; mi < 2; mi++) {
        #pragma unroll
        for (int ni = 0; ni < 2; ni++) {
            f32x4 acc = (mi == 0) ? (ni == 0 ? acc00 : acc01)
                                  : (ni == 0 ? acc10 : acc11);
            #pragma unroll
            for (int rg = 0; rg < 4; rg++) {
                int row = tile_m + wm + mi * 16 + (lane >> 4) * 4 + rg;
                int col = tile_n + wn + ni * 16 + (lane & 15);
                float v = acc[rg];
                if (bias) v += bias[col];
                if (act == 1) v = tanhf(v);
                long oidx = (long)bz * out_bstride + (long)row * N + col;
                if (outb) outb[oidx] = f2bf(v);
                else outf[oidx] = v;
            }
        }
    }
}

// ---------------------------------------------------------------------------
// Persistent LSTM recurrence, 64 blocks x 512 threads (8 waves).
// bg = blockIdx>>4 owns batches [bg*16,+16); nb = blockIdx&15 owns cols
// [nb*32,+32) of every gate (128 W_hh rows, in registers: 16 bf16x8/lane).
// R7 sync: per-publisher epoch flags, 256B apart. Publisher (after data
// stores drained by __syncthreads) release-stores flag=t+1 into slot t&1.
// Consumer wave 0, lanes 0..15 acquire-poll the 16 flags of slot (t-1)&1
// until all >= t (ballot). No RMW, no shared cacheline.
// ---------------------------------------------------------------------------
#define WSTRIDE 520
#define HEXCH 4096
#define FLSTRIDE 64   // dwords between flags = 256 B
#define ZL(g,r,d) zl[((g)*16+(r))*33+(d)]

__global__ __launch_bounds__(512)
void persistent_lstm(const float* __restrict__ Whh,         // f32 [2048][512]
                     const unsigned short* __restrict__ Zx, // bf16 [16384][2048]
                     unsigned short* __restrict__ Hs,       // bf16 [64][256][512]
                     unsigned int* __restrict__ HexU32,     // [2][4][4096] dwords
                     int* __restrict__ flags)               // [2][4][16] @ 256B stride
{
    __shared__ __align__(16) unsigned short hsm[16 * WSTRIDE];  // 16,640 B
    __shared__ float zl[4 * 16 * 33];                           //  8,448 B

    const int bg = blockIdx.x >> 4;
    const int nb = blockIdx.x & 15;
    const int tid = threadIdx.x;
    const int w = tid >> 6;        // 0..7
    const int lane = tid & 63;
    const int fr = lane & 15;
    const int fq = (lane >> 4) * 8;
    const int g = w >> 1;          // gate
    const int f = w & 1;           // 16-row fragment within gate's 32 cols

    // ---- one-time: this wave's W_hh fragment rows into registers ----
    bf16x8 wfrag[16];
    {
        const float* wrow = Whh + (long)(g * 512 + nb * 32 + f * 16 + fr) * 512;
        #pragma unroll
        for (int c = 0; c < 16; c++) {
            int k0 = c * 32 + fq;
            float4 u0 = *(const float4*)(wrow + k0);
            float4 u1 = *(const float4*)(wrow + k0 + 4);
            unsigned short tmp[8] __attribute__((aligned(16)));
            tmp[0] = f2bf(u0.x); tmp[1] = f2bf(u0.y); tmp[2] = f2bf(u0.z); tmp[3] = f2bf(u0.w);
            tmp[4] = f2bf(u1.x); tmp[5] = f2bf(u1.y); tmp[6] = f2bf(u1.z); tmp[7] = f2bf(u1.w);
            wfrag[c] = *(const bf16x8*)tmp;
        }
    }

    // gate-math ownership (threads 0..255): row grow, col pair (d0, d0+1)
    const int grow = (tid & 255) >> 4;
    const int d0 = (tid & 15) * 2;
    const int b_own = bg * 16 + grow;
    const int dg = nb * 32 + d0;
    float ca = 0.f, cb = 0.f;      // cell state in registers (threads < 256)

    f32x4 zero4 = {0.f, 0.f, 0.f, 0.f};

    for (int t = 0; t < T_; t++) {
        // Zx gate pre-activations: independent of h -> load early
        unsigned zi_u = 0, zf_u = 0, zg_u = 0, zo_u = 0;
        if (tid < 256) {
            const long zb = ((long)b_own * T_ + t) * H4 + dg;
            zi_u = *(const unsigned*)&Zx[zb + 0 * 512];
            zf_u = *(const unsigned*)&Zx[zb + 1 * 512];
            zg_u = *(const unsigned*)&Zx[zb + 2 * 512];
            zo_u = *(const unsigned*)&Zx[zb + 3 * 512];
        }

        f32x4 acc = zero4;
        if (t > 0) {
            // wait for all 16 publishers of slot (t-1)&1 to reach epoch >= t
            if (tid < 64) {
                const int* fl = flags + ((((t - 1) & 1) * 4 + bg) * 16 + (lane & 15)) * FLSTRIDE;
                const bool need = lane < 16;
                while (true) {
                    int v = need ? __hip_atomic_load(fl, __ATOMIC_ACQUIRE,
                                                     __HIP_MEMORY_SCOPE_AGENT)
                                 : 0x7fffffff;
                    if (!__ballot(need && (v < t))) break;
                    __builtin_amdgcn_s_sleep(1);
                }
            }
            __syncthreads();
            // stage h_{t-1} (16 batches x 512 cols = 4096 dwords) from slot (t-1)&1
            // chunk dword layout (writer nb'=p): p*256 + r*16 + cpl
            //   -> h[bg*16+r][p*32 + cpl*2 .. +1]
            const unsigned int* hexbase = HexU32 + (((t - 1) & 1) * 4 + bg) * HEXCH;
            #pragma unroll
            for (int it = 0; it < 8; it++) {
                int idx = it * 512 + tid;          // 0..4095
                int p = idx >> 8;
                int local = idx & 255;
                int r = local >> 4;
                int cpl = local & 15;
                unsigned int v = __hip_atomic_load(hexbase + idx,
                                                   __ATOMIC_RELAXED, __HIP_MEMORY_SCOPE_AGENT);
                *(unsigned int*)&hsm[r * WSTRIDE + p * 32 + cpl * 2] = v;
            }
            __syncthreads();
            // z_frag = h_{t-1}[16x512] @ Wfrag^T : 16 MFMAs over K=512
            const unsigned short* arow = hsm + fr * WSTRIDE;
            #pragma unroll
            for (int c = 0; c < 16; c++) {
                bf16x8 a = *(const bf16x8*)(arow + c * 32 + fq);
                acc = __builtin_amdgcn_mfma_f32_16x16x32_bf16(a, wfrag[c], acc, 0, 0, 0);
            }
        }
        // scatter z to LDS (C/D: col=lane&15, row=(lane>>4)*4+reg)
        {
            const int q4 = (lane >> 4) * 4;
            const int cl = f * 16 + (lane & 15);
            #pragma unroll
            for (int rg = 0; rg < 4; rg++) {
                ZL(g, q4 + rg, cl) = acc[rg];
            }
        }
        __syncthreads();
        // gate math on threads 0..255 (wave-uniform branch)
        if (tid < 256) {
            float zi0 = ZL(0, grow, d0)     + bf2f_lo(zi_u);
            float zi1 = ZL(0, grow, d0 + 1) + bf2f_hi(zi_u);
            float zf0 = ZL(1, grow, d0)     + bf2f_lo(zf_u);
            float zf1 = ZL(1, grow, d0 + 1) + bf2f_hi(zf_u);
            float zg0 = ZL(2, grow, d0)     + bf2f_lo(zg_u);
            float zg1 = ZL(2, grow, d0 + 1) + bf2f_hi(zg_u);
            float zo0 = ZL(3, grow, d0)     + bf2f_lo(zo_u);
            float zo1 = ZL(3, grow, d0 + 1) + bf2f_hi(zo_u);

            ca = sigmoidf_(zf0) * ca + sigmoidf_(zi0) * tanhf(zg0);
            cb = sigmoidf_(zf1) * cb + sigmoidf_(zi1) * tanhf(zg1);
            float h0 = sigmoidf_(zo0) * tanhf(ca);
            float h1 = sigmoidf_(zo1) * tanhf(cb);

            unsigned hp = (unsigned)f2bf(h0) | ((unsigned)f2bf(h1) << 16);
            // history (plain store; consumed only after kernel completion)
            *(unsigned*)&Hs[((long)b_own * T_ + t) * D_ + dg] = hp;
            // publish to exchange slot t&1 (agent scope); index nb*256+tid < 4096
            __hip_atomic_store(HexU32 + ((t & 1) * 4 + bg) * HEXCH + nb * 256 + (tid & 255),
                               hp, __ATOMIC_RELAXED, __HIP_MEMORY_SCOPE_AGENT);
        }
        __syncthreads();   // vmcnt(0) before barrier -> publishes drained
        if (tid == 0) {
            // epoch flag: h_t available in slot t&1 (values 1,3,5../2,4,6..)
            __hip_atomic_store(flags + (((t & 1) * 4 + bg) * 16 + nb) * FLSTRIDE,
                               t + 1, __ATOMIC_RELEASE, __HIP_MEMORY_SCOPE_AGENT);
        }
    }
}

// ---------------------------------------------------------------------------
// Aspect normalization (unchanged)
// ---------------------------------------------------------------------------
__global__ __launch_bounds__(64)
void aspect_norm(const int* __restrict__ s,
                 const float* __restrict__ embed,
                 float* __restrict__ s_norm)
{
    __shared__ int sidx[256];
    const int tid = threadIdx.x;
    const int d = blockIdx.x * 64 + tid;
    for (int i = tid; i < 256; i += 64) sidx[i] = s[i];
    __syncthreads();
    float sum = 0.f, sq = 0.f;
    for (int i = 0; i < 256; i++) {
        float v = embed[(long)sidx[i] * D_ + d];
        sum += v; sq += v * v;
    }
    float mu = sum * (1.f / 256.f);
    float var = sq * (1.f / 256.f) - mu * mu;
    float rstd = rsqrtf(var + 1e-5f);
    for (int b = 0; b < 64; b++) {
        float acc = 0.f;
        #pragma unroll
        for (int a = 0; a < 4; a++) {
            acc += embed[(long)sidx[b * 4 + a] * D_ + d] - mu;
        }
        s_norm[b * D_ + d] = acc * rstd;
    }
}

// ---------------------------------------------------------------------------
// Softmax over T + r reduction (unchanged)
// ---------------------------------------------------------------------------
__global__ __launch_bounds__(256)
void attn_r(const float* __restrict__ apre,
            const unsigned short* __restrict__ Hs,
            float* __restrict__ r)
{
    const int b = blockIdx.y;
    const int d = blockIdx.x * 256 + threadIdx.x;
    const float* ap = apre + (long)b * T_ * D_ + d;
    const unsigned short* hp = Hs + (long)b * T_ * D_ + d;
    float mx = ap[0], sm = 1.f;
    for (int t = 1; t < T_; t++) {
        float v = ap[(long)t * D_];
        if (v > mx) { sm = sm * expf(mx - v) + 1.f; mx = v; }
        else sm += expf(v - mx);
    }
    float acc = 0.f;
    for (int t = 0; t < T_; t++) {
        acc += expf(ap[(long)t * D_] - mx) * bf2f(hp[(long)t * D_]);
    }
    r[b * D_ + d] = acc / sm;
}

// ---------------------------------------------------------------------------
// h_star = tanh(r @ w_p^T + Hs[:, -1] @ w_x^T) (unchanged)
// ---------------------------------------------------------------------------
__global__ __launch_bounds__(256)
void hstar_kernel(const float* __restrict__ r,
                  const unsigned short* __restrict__ Hs,
                  const float* __restrict__ w_p,
                  const float* __restrict__ w_x,
                  float* __restrict__ h_star)
{
    __shared__ float rs[512];
    __shared__ float hts[512];
    const int b = blockIdx.x, tid = threadIdx.x;
    const long hlast = ((long)b * T_ + (T_ - 1)) * D_;
    rs[tid] = r[b * D_ + tid];
    rs[tid + 256] = r[b * D_ + 256 + tid];
    hts[tid] = bf2f(Hs[hlast + tid]);
    hts[tid + 256] = bf2f(Hs[hlast + 256 + tid]);
    __syncthreads();
    for (int d = tid; d < 512; d += 256) {
        const float* wp = w_p + (long)d * D_;
        const float* wx = w_x + (long)d * D_;
        float acc = 0.f;
        for (int e = 0; e < 512; e += 4) {
            float4 p1 = *(const float4*)(wp + e);
            float4 p2 = *(const float4*)(wx + e);
            acc += p1.x * rs[e] + p1.y * rs[e + 1] + p1.z * rs[e + 2] + p1.w * rs[e + 3];
            acc += p2.x * hts[e] + p2.y * hts[e + 1] + p2.z * hts[e + 2] + p2.w * hts[e + 3];
        }
        h_star[b * D_ + d] = tanhf(acc);
    }
}

// ---------------------------------------------------------------------------
// out = softmax(h_star @ w_f^T + b_f) (unchanged)
// ---------------------------------------------------------------------------
__global__ __launch_bounds__(256)
void out_kernel(const float* __restrict__ h_star,
                const float* __restrict__ w_f,
                const float* __restrict__ b_f,
                float* __restrict__ out)
{
    __shared__ float hs[512];
    __shared__ float lg[512];
    __shared__ float red[8];
    const int b = blockIdx.x, tid = threadIdx.x;
    hs[tid] = h_star[b * D_ + tid];
    hs[tid + 256] = h_star[b * D_ + 256 + tid];
    __syncthreads();
    for (int d = tid; d < 512; d += 256) {
        const float* wr = w_f + (long)d * D_;
        float acc = b_f[d];
        for (int e = 0; e < 512; e += 4) {
            float4 p = *(const float4*)(wr + e);
            acc += p.x * hs[e] + p.y * hs[e + 1] + p.z * hs[e + 2] + p.w * hs[e + 3];
        }
        lg[d] = acc;
    }
    __syncthreads();
    float m0 = fmaxf(lg[tid], lg[tid + 256]);
    for (int off = 32; off > 0; off >>= 1) m0 = fmaxf(m0, __shfl_down(m0, off, 64));
    if ((tid & 63) == 0) red[tid >> 6] = m0;
    __syncthreads();
    float bmax = fmaxf(fmaxf(red[0], red[1]), fmaxf(red[2], red[3]));
    float e0 = expf(lg[tid] - bmax);
    float e1 = expf(lg[tid + 256] - bmax);
    float s0 = e0 + e1;
    for (int off = 32; off > 0; off >>= 1) s0 += __shfl_down(s0, off, 64);
    if ((tid & 63) == 0) red[4 + (tid >> 6)] = s0;
    __syncthreads();
    float inv = 1.f / (red[4] + red[5] + red[6] + red[7]);
    out[b * D_ + tid] = e0 * inv;
    out[b * D_ + 256 + tid] = e1 * inv;
}

// ---------------------------------------------------------------------------
extern "C" void kernel_launch(void* const* d_in, const int* in_sizes, int n_in,
                              void* d_out, int out_size, void* d_ws, size_t ws_size,
                              hipStream_t stream)
{
    (void)in_sizes; (void)n_in; (void)out_size; (void)ws_size;

    const int* x = (const int*)d_in[0];
    const int* s = (const int*)d_in[1];
    const float* embed  = (const float*)d_in[2];
    const float* W_ih   = (const float*)d_in[3];
    const float* W_hh   = (const float*)d_in[4];
    const float* b_lstm = (const float*)d_in[5];
    const float* w_y = (const float*)d_in[6];
    const float* w_t = (const float*)d_in[7];
    const float* w_p = (const float*)d_in[8];
    const float* w_x = (const float*)d_in[9];
    const float* w_f = (const float*)d_in[10];
    const float* b_f = (const float*)d_in[11];

    // Workspace (overlaid), peak ~86.5 MB:
    //   [0,64MiB)   phase1: Zx bf16 [16384][2048]
    //               phase2: apre f32 @0, mbuf bf16 @32MiB, Ybuf bf16 @48MiB
    //   [64MiB,+16MiB) Hs bf16
    //   @83886080: Hex [2][4][4096] dwords = 131072 B
    //   @84017152: flags [2][4][16] @256B stride = 32768 B
    //   @86114304: s_norm, @86245376: rbuf, @86376448: hstar
    char* ws = (char*)d_ws;
    unsigned short* Zx   = (unsigned short*)(ws + 0);
    float*          apre = (float*)(ws + 0);
    unsigned short* mbuf = (unsigned short*)(ws + 33554432);
    unsigned short* Ybuf = (unsigned short*)(ws + 50331648);
    unsigned short* Hs   = (unsigned short*)(ws + 67108864);
    unsigned int*   Hex  = (unsigned int*)(ws + 83886080);
    int*            flags = (int*)(ws + 84017152);
    float* s_norm = (float*)(ws + 86114304);
    float* rbuf   = (float*)(ws + 86245376);
    float* hstar  = (float*)(ws + 86376448);

    // 0) zero the epoch flags (ws is re-poisoned before every launch)
    hipMemsetAsync(flags, 0, 32768, stream);

    // 1) aspect normalization
    aspect_norm<<<dim3(8), dim3(64), 0, stream>>>(s, embed, s_norm);

    // 2) G1: Zx = embed[x] @ W_ih^T + b_lstm  (M=16384, N=2048, K=512)
    gemm_bt<<<dim3(32, 256, 1), dim3(256), 0, stream>>>(
        embed, 1, x, W_ih, nullptr, b_lstm, Zx, nullptr,
        2048, 512, 0L, 0L, 0);

    // 3) recurrence: ONE persistent kernel, 64 blocks x 512 threads
    persistent_lstm<<<dim3(64), dim3(512), 0, stream>>>(
        W_hh, Zx, Hs, Hex, flags);

    // ---- phase 2: Zx dead; region reused for apre/mbuf/Ybuf ----

    // 4) G2: m[b] = Hs[b] @ circ(s_norm[b])^T
    gemm_bt<<<dim3(8, 4, 64), dim3(256), 0, stream>>>(
        Hs, 0, nullptr, nullptr, s_norm, nullptr, mbuf, nullptr,
        512, 512, (long)(T_ * D_), (long)(T_ * D_), 0);

    // 5) G3: Y = tanh(m @ w_y^T)
    gemm_bt<<<dim3(8, 256, 1), dim3(256), 0, stream>>>(
        mbuf, 0, nullptr, w_y, nullptr, nullptr, Ybuf, nullptr,
        512, 512, 0L, 0L, 1);

    // 6) G4: apre = Y @ w_t^T
    gemm_bt<<<dim3(8, 256, 1), dim3(256), 0, stream>>>(
        Ybuf, 0, nullptr, w_t, nullptr, nullptr, nullptr, apre,
        512, 512, 0L, 0L, 0);

    // 7) softmax over T + r reduction
    attn_r<<<dim3(2, 64), dim3(256), 0, stream>>>(apre, Hs, rbuf);

    // 8) h_star
    hstar_kernel<<<dim3(64), dim3(256), 0, stream>>>(rbuf, Hs, w_p, w_x, hstar);

    // 9) final logits + softmax
    out_kernel<<<dim3(64), dim3(256), 0, stream>>>(hstar, w_f, b_f, (float*)d_out);
}

// Round 8
// 1388.344 us; speedup vs baseline: 2.0302x; 1.3883x over previous
//
#include <hip/hip_runtime.h>

// AF-LSTM on MI355X. Sizes fixed: V=32000, D=H=512, B=64, T=256, A=4, 4H=2048.
// All float tensors f32; x,s int32; d_out f32 [64,512].
// R7: 1927us; persistent_lstm 1294us (5us/step), FETCH 141MB >> 71MB ideal.
// Diagnosis: agent-scope ACQUIRE polls emit L2 invalidates every iteration and
// RELEASE flag-stores emit L2 writebacks (gfx950 SIMemoryLegalizer) -> cache
// thrash + serialization. R8: sentinel-based direct data polling. Publishers
// store h straight into Hs (relaxed agent, write-through); Hs pre-memset to
// 0xFFFFFFFF (bf16 NaN pair, unreachable for tanh*sigmoid outputs); consumers
// relaxed-poll the exact dwords they need. No fences, no flags, no lockstep.

typedef __bf16 bf16x8 __attribute__((ext_vector_type(8)));
typedef float f32x4 __attribute__((ext_vector_type(4)));

#define B_ 64
#define T_ 256
#define D_ 512
#define H4 2048

__device__ __forceinline__ unsigned short f2bf(float f) {
    unsigned u = __float_as_uint(f);
    u += 0x7fffu + ((u >> 16) & 1u);   // round-to-nearest-even
    return (unsigned short)(u >> 16);
}
__device__ __forceinline__ float bf2f(unsigned short x) {
    return __uint_as_float(((unsigned)x) << 16);
}
__device__ __forceinline__ float bf2f_lo(unsigned u) { return __uint_as_float(u << 16); }
__device__ __forceinline__ float bf2f_hi(unsigned u) { return __uint_as_float(u & 0xffff0000u); }
__device__ __forceinline__ float sigmoidf_(float x) {
    return 1.f / (1.f + expf(-x));
}

// ---------------------------------------------------------------------------
// C = A @ B^T GEMM, bf16 MFMA 16x16x32, 64x64 block tile, 4 waves.
// (unchanged from the round-3 passing version)
// ---------------------------------------------------------------------------
__global__ __launch_bounds__(256)
void gemm_bt(const void* __restrict__ Abase, int a_f32,
             const int* __restrict__ gather_idx,
             const float* __restrict__ Bmat,
             const float* __restrict__ circ_src,
             const float* __restrict__ bias,
             unsigned short* __restrict__ outb,
             float* __restrict__ outf,
             int N, int K,
             long A_bstride, long out_bstride,
             int act)
{
    __shared__ __align__(16) unsigned short Asm[64 * 40];
    __shared__ __align__(16) unsigned short Bsm[64 * 40];

    const int bz = blockIdx.z;
    const int tile_n = blockIdx.x * 64;
    const int tile_m = blockIdx.y * 64;
    const int tid = threadIdx.x;
    const int lane = tid & 63;
    const int w = tid >> 6;
    const int wm = (w >> 1) * 32;
    const int wn = (w & 1) * 32;

    const int srow = tid >> 2;
    const int skc = (tid & 3) * 8;

    const float* arow_f = nullptr;
    const unsigned short* arow_h = nullptr;
    if (a_f32) {
        const float* Af = (const float*)Abase;
        if (gather_idx) arow_f = Af + (long)gather_idx[tile_m + srow] * K;
        else            arow_f = Af + (long)bz * A_bstride + (long)(tile_m + srow) * K;
    } else {
        arow_h = (const unsigned short*)Abase + (long)bz * A_bstride + (long)(tile_m + srow) * K;
    }
    const float* brow = nullptr;
    const float* csrc = nullptr;
    if (circ_src) csrc = circ_src + bz * 512;
    else brow = Bmat + (long)(tile_n + srow) * K;

    f32x4 zero4 = {0.f, 0.f, 0.f, 0.f};
    f32x4 acc00 = zero4, acc01 = zero4, acc10 = zero4, acc11 = zero4;

    const int fr = lane & 15;
    const int fq = (lane >> 4) * 8;

    for (int kc = 0; kc < K; kc += 32) {
        __syncthreads();
        if (a_f32) {
            float4 u0 = *(const float4*)(arow_f + kc + skc);
            float4 u1 = *(const float4*)(arow_f + kc + skc + 4);
            unsigned short tmp[8] __attribute__((aligned(16)));
            tmp[0] = f2bf(u0.x); tmp[1] = f2bf(u0.y); tmp[2] = f2bf(u0.z); tmp[3] = f2bf(u0.w);
            tmp[4] = f2bf(u1.x); tmp[5] = f2bf(u1.y); tmp[6] = f2bf(u1.z); tmp[7] = f2bf(u1.w);
            *(uint4*)&Asm[srow * 40 + skc] = *(const uint4*)tmp;
        } else {
            *(uint4*)&Asm[srow * 40 + skc] = *(const uint4*)(arow_h + kc + skc);
        }
        if (csrc) {
            unsigned short tmp[8] __attribute__((aligned(16)));
            int n_abs = tile_n + srow;
            #pragma unroll
            for (int j = 0; j < 8; j++) {
                int k_abs = kc + skc + j;
                tmp[j] = f2bf(csrc[(k_abs - n_abs) & 511]);
            }
            *(uint4*)&Bsm[srow * 40 + skc] = *(const uint4*)tmp;
        } else {
            float4 u0 = *(const float4*)(brow + kc + skc);
            float4 u1 = *(const float4*)(brow + kc + skc + 4);
            unsigned short tmp[8] __attribute__((aligned(16)));
            tmp[0] = f2bf(u0.x); tmp[1] = f2bf(u0.y); tmp[2] = f2bf(u0.z); tmp[3] = f2bf(u0.w);
            tmp[4] = f2bf(u1.x); tmp[5] = f2bf(u1.y); tmp[6] = f2bf(u1.z); tmp[7] = f2bf(u1.w);
            *(uint4*)&Bsm[srow * 40 + skc] = *(const uint4*)tmp;
        }
        __syncthreads();
        bf16x8 a0 = *(const bf16x8*)&Asm[(wm + fr) * 40 + fq];
        bf16x8 a1 = *(const bf16x8*)&Asm[(wm + 16 + fr) * 40 + fq];
        bf16x8 b0 = *(const bf16x8*)&Bsm[(wn + fr) * 40 + fq];
        bf16x8 b1 = *(const bf16x8*)&Bsm[(wn + 16 + fr) * 40 + fq];
        acc00 = __builtin_amdgcn_mfma_f32_16x16x32_bf16(a0, b0, acc00, 0, 0, 0);
        acc01 = __builtin_amdgcn_mfma_f32_16x16x32_bf16(a0, b1, acc01, 0, 0, 0);
        acc10 = __builtin_amdgcn_mfma_f32_16x16x32_bf16(a1, b0, acc10, 0, 0, 0);
        acc11 = __builtin_amdgcn_mfma_f32_16x16x32_bf16(a1, b1, acc11, 0, 0, 0);
    }

    #pragma unroll
    for (int mi = 0; mi < 2; mi++) {
        #pragma unroll
        for (int ni = 0; ni < 2; ni++) {
            f32x4 acc = (mi == 0) ? (ni == 0 ? acc00 : acc01)
                                  : (ni == 0 ? acc10 : acc11);
            #pragma unroll
            for (int rg = 0; rg < 4; rg++) {
                int row = tile_m + wm + mi * 16 + (lane >> 4) * 4 + rg;
                int col = tile_n + wn + ni * 16 + (lane & 15);
                float v = acc[rg];
                if (bias) v += bias[col];
                if (act == 1) v = tanhf(v);
                long oidx = (long)bz * out_bstride + (long)row * N + col;
                if (outb) outb[oidx] = f2bf(v);
                else outf[oidx] = v;
            }
        }
    }
}

// ---------------------------------------------------------------------------
// Persistent LSTM recurrence, 64 blocks x 512 threads (8 waves).
// bg = blockIdx>>4 owns batches [bg*16,+16); nb = blockIdx&15 owns cols
// [nb*32,+32) of every gate (128 W_hh rows in registers: 16 bf16x8/lane).
// R8 sync: NO flags, NO fences. h_t stored directly into Hs (relaxed agent,
// write-through to coherence point). Hs pre-filled with 0xFFFFFFFF (bf16
// NaN pair -- h=sigmoid*tanh can never produce it). Consumers poll exactly
// the 4096 dwords of Hs[:, t-1, :] they need until non-sentinel, reloading
// only pending ones. Each block self-paces on true data dependencies.
// ---------------------------------------------------------------------------
#define WSTRIDE 520
#define SENT 0xFFFFFFFFu
#define ZL(g,r,d) zl[((g)*16+(r))*33+(d)]

__global__ __launch_bounds__(512)
void persistent_lstm(const float* __restrict__ Whh,         // f32 [2048][512]
                     const unsigned short* __restrict__ Zx, // bf16 [16384][2048]
                     unsigned int* __restrict__ Hsu)        // Hs as dwords [64*256*256]
{
    __shared__ __align__(16) unsigned short hsm[16 * WSTRIDE];  // 16,640 B
    __shared__ float zl[4 * 16 * 33];                           //  8,448 B

    const int bg = blockIdx.x >> 4;
    const int nb = blockIdx.x & 15;
    const int tid = threadIdx.x;
    const int w = tid >> 6;        // 0..7
    const int lane = tid & 63;
    const int fr = lane & 15;
    const int fq = (lane >> 4) * 8;
    const int g = w >> 1;          // gate
    const int f = w & 1;           // 16-row fragment within gate's 32 cols

    // ---- one-time: this wave's W_hh fragment rows into registers ----
    bf16x8 wfrag[16];
    {
        const float* wrow = Whh + (long)(g * 512 + nb * 32 + f * 16 + fr) * 512;
        #pragma unroll
        for (int c = 0; c < 16; c++) {
            int k0 = c * 32 + fq;
            float4 u0 = *(const float4*)(wrow + k0);
            float4 u1 = *(const float4*)(wrow + k0 + 4);
            unsigned short tmp[8] __attribute__((aligned(16)));
            tmp[0] = f2bf(u0.x); tmp[1] = f2bf(u0.y); tmp[2] = f2bf(u0.z); tmp[3] = f2bf(u0.w);
            tmp[4] = f2bf(u1.x); tmp[5] = f2bf(u1.y); tmp[6] = f2bf(u1.z); tmp[7] = f2bf(u1.w);
            wfrag[c] = *(const bf16x8*)tmp;
        }
    }

    // staging ownership: thread handles 8 dwords; idx = it*512+tid,
    // r = idx>>8 (batch row 0..15), dpair = idx&255 (col pair 0..255)
    int st_r[8], st_dp[8];
    #pragma unroll
    for (int it = 0; it < 8; it++) {
        int idx = it * 512 + tid;
        st_r[it] = idx >> 8;
        st_dp[it] = idx & 255;
    }

    // gate-math ownership (threads 0..255): row grow, col pair (d0, d0+1)
    const int grow = (tid & 255) >> 4;
    const int d0 = (tid & 15) * 2;
    const int b_own = bg * 16 + grow;
    const int dg = nb * 32 + d0;
    float ca = 0.f, cb = 0.f;      // cell state in registers (threads < 256)

    f32x4 zero4 = {0.f, 0.f, 0.f, 0.f};

    for (int t = 0; t < T_; t++) {
        // Zx gate pre-activations: independent of h -> issue early
        unsigned zi_u = 0, zf_u = 0, zg_u = 0, zo_u = 0;
        if (tid < 256) {
            const long zb = ((long)b_own * T_ + t) * H4 + dg;
            zi_u = *(const unsigned*)&Zx[zb + 0 * 512];
            zf_u = *(const unsigned*)&Zx[zb + 1 * 512];
            zg_u = *(const unsigned*)&Zx[zb + 2 * 512];
            zo_u = *(const unsigned*)&Zx[zb + 3 * 512];
        }

        f32x4 acc = zero4;
        if (t > 0) {
            // poll-stage h_{t-1}: 4096 dwords of Hs[bg*16..+16][t-1][*]
            unsigned vv[8];
            long ad[8];
            #pragma unroll
            for (int it = 0; it < 8; it++) {
                ad[it] = ((long)(bg * 16 + st_r[it]) * T_ + (t - 1)) * 256 + st_dp[it];
                vv[it] = __hip_atomic_load(Hsu + ad[it], __ATOMIC_RELAXED,
                                           __HIP_MEMORY_SCOPE_AGENT);
            }
            while (true) {
                bool pend = false;
                #pragma unroll
                for (int it = 0; it < 8; it++) {
                    if (vv[it] == SENT) {
                        vv[it] = __hip_atomic_load(Hsu + ad[it], __ATOMIC_RELAXED,
                                                   __HIP_MEMORY_SCOPE_AGENT);
                        pend = true;
                    }
                }
                if (!__ballot(pend)) break;
                __builtin_amdgcn_s_sleep(1);
            }
            #pragma unroll
            for (int it = 0; it < 8; it++) {
                *(unsigned*)&hsm[st_r[it] * WSTRIDE + st_dp[it] * 2] = vv[it];
            }
            __syncthreads();   // S1: hsm staged (also fences prev-iter zl reads)
            // z_frag = h_{t-1}[16x512] @ Wfrag^T : 16 MFMAs over K=512
            const unsigned short* arow = hsm + fr * WSTRIDE;
            #pragma unroll
            for (int c = 0; c < 16; c++) {
                bf16x8 a = *(const bf16x8*)(arow + c * 32 + fq);
                acc = __builtin_amdgcn_mfma_f32_16x16x32_bf16(a, wfrag[c], acc, 0, 0, 0);
            }
        }
        // scatter z to LDS (C/D: col=lane&15, row=(lane>>4)*4+reg)
        {
            const int q4 = (lane >> 4) * 4;
            const int cl = f * 16 + (lane & 15);
            #pragma unroll
            for (int rg = 0; rg < 4; rg++) {
                ZL(g, q4 + rg, cl) = acc[rg];
            }
        }
        __syncthreads();       // S2: zl complete (and hsm reads drained)
        // gate math on threads 0..255 (wave-uniform branch)
        if (tid < 256) {
            float zi0 = ZL(0, grow, d0)     + bf2f_lo(zi_u);
            float zi1 = ZL(0, grow, d0 + 1) + bf2f_hi(zi_u);
            float zf0 = ZL(1, grow, d0)     + bf2f_lo(zf_u);
            float zf1 = ZL(1, grow, d0 + 1) + bf2f_hi(zf_u);
            float zg0 = ZL(2, grow, d0)     + bf2f_lo(zg_u);
            float zg1 = ZL(2, grow, d0 + 1) + bf2f_hi(zg_u);
            float zo0 = ZL(3, grow, d0)     + bf2f_lo(zo_u);
            float zo1 = ZL(3, grow, d0 + 1) + bf2f_hi(zo_u);

            ca = sigmoidf_(zf0) * ca + sigmoidf_(zi0) * tanhf(zg0);
            cb = sigmoidf_(zf1) * cb + sigmoidf_(zi1) * tanhf(zg1);
            float h0 = sigmoidf_(zo0) * tanhf(ca);
            float h1 = sigmoidf_(zo1) * tanhf(cb);

            unsigned hp = (unsigned)f2bf(h0) | ((unsigned)f2bf(h1) << 16);
            // publish: history and exchange in one store (write-through)
            __hip_atomic_store(Hsu + ((long)b_own * T_ + t) * 256 + nb * 16 + (tid & 15),
                               hp, __ATOMIC_RELAXED, __HIP_MEMORY_SCOPE_AGENT);
        }
        // no trailing sync: S1 of the next iteration protects zl reuse
    }
}

// ---------------------------------------------------------------------------
// Aspect normalization (unchanged)
// ---------------------------------------------------------------------------
__global__ __launch_bounds__(64)
void aspect_norm(const int* __restrict__ s,
                 const float* __restrict__ embed,
                 float* __restrict__ s_norm)
{
    __shared__ int sidx[256];
    const int tid = threadIdx.x;
    const int d = blockIdx.x * 64 + tid;
    for (int i = tid; i < 256; i += 64) sidx[i] = s[i];
    __syncthreads();
    float sum = 0.f, sq = 0.f;
    for (int i = 0; i < 256; i++) {
        float v = embed[(long)sidx[i] * D_ + d];
        sum += v; sq += v * v;
    }
    float mu = sum * (1.f / 256.f);
    float var = sq * (1.f / 256.f) - mu * mu;
    float rstd = rsqrtf(var + 1e-5f);
    for (int b = 0; b < 64; b++) {
        float acc = 0.f;
        #pragma unroll
        for (int a = 0; a < 4; a++) {
            acc += embed[(long)sidx[b * 4 + a] * D_ + d] - mu;
        }
        s_norm[b * D_ + d] = acc * rstd;
    }
}

// ---------------------------------------------------------------------------
// Softmax over T + r reduction (unchanged)
// ---------------------------------------------------------------------------
__global__ __launch_bounds__(256)
void attn_r(const float* __restrict__ apre,
            const unsigned short* __restrict__ Hs,
            float* __restrict__ r)
{
    const int b = blockIdx.y;
    const int d = blockIdx.x * 256 + threadIdx.x;
    const float* ap = apre + (long)b * T_ * D_ + d;
    const unsigned short* hp = Hs + (long)b * T_ * D_ + d;
    float mx = ap[0], sm = 1.f;
    for (int t = 1; t < T_; t++) {
        float v = ap[(long)t * D_];
        if (v > mx) { sm = sm * expf(mx - v) + 1.f; mx = v; }
        else sm += expf(v - mx);
    }
    float acc = 0.f;
    for (int t = 0; t < T_; t++) {
        acc += expf(ap[(long)t * D_] - mx) * bf2f(hp[(long)t * D_]);
    }
    r[b * D_ + d] = acc / sm;
}

// ---------------------------------------------------------------------------
// h_star = tanh(r @ w_p^T + Hs[:, -1] @ w_x^T) (unchanged)
// ---------------------------------------------------------------------------
__global__ __launch_bounds__(256)
void hstar_kernel(const float* __restrict__ r,
                  const unsigned short* __restrict__ Hs,
                  const float* __restrict__ w_p,
                  const float* __restrict__ w_x,
                  float* __restrict__ h_star)
{
    __shared__ float rs[512];
    __shared__ float hts[512];
    const int b = blockIdx.x, tid = threadIdx.x;
    const long hlast = ((long)b * T_ + (T_ - 1)) * D_;
    rs[tid] = r[b * D_ + tid];
    rs[tid + 256] = r[b * D_ + 256 + tid];
    hts[tid] = bf2f(Hs[hlast + tid]);
    hts[tid + 256] = bf2f(Hs[hlast + 256 + tid]);
    __syncthreads();
    for (int d = tid; d < 512; d += 256) {
        const float* wp = w_p + (long)d * D_;
        const float* wx = w_x + (long)d * D_;
        float acc = 0.f;
        for (int e = 0; e < 512; e += 4) {
            float4 p1 = *(const float4*)(wp + e);
            float4 p2 = *(const float4*)(wx + e);
            acc += p1.x * rs[e] + p1.y * rs[e + 1] + p1.z * rs[e + 2] + p1.w * rs[e + 3];
            acc += p2.x * hts[e] + p2.y * hts[e + 1] + p2.z * hts[e + 2] + p2.w * hts[e + 3];
        }
        h_star[b * D_ + d] = tanhf(acc);
    }
}

// ---------------------------------------------------------------------------
// out = softmax(h_star @ w_f^T + b_f) (unchanged)
// ---------------------------------------------------------------------------
__global__ __launch_bounds__(256)
void out_kernel(const float* __restrict__ h_star,
                const float* __restrict__ w_f,
                const float* __restrict__ b_f,
                float* __restrict__ out)
{
    __shared__ float hs[512];
    __shared__ float lg[512];
    __shared__ float red[8];
    const int b = blockIdx.x, tid = threadIdx.x;
    hs[tid] = h_star[b * D_ + tid];
    hs[tid + 256] = h_star[b * D_ + 256 + tid];
    __syncthreads();
    for (int d = tid; d < 512; d += 256) {
        const float* wr = w_f + (long)d * D_;
        float acc = b_f[d];
        for (int e = 0; e < 512; e += 4) {
            float4 p = *(const float4*)(wr + e);
            acc += p.x * hs[e] + p.y * hs[e + 1] + p.z * hs[e + 2] + p.w * hs[e + 3];
        }
        lg[d] = acc;
    }
    __syncthreads();
    float m0 = fmaxf(lg[tid], lg[tid + 256]);
    for (int off = 32; off > 0; off >>= 1) m0 = fmaxf(m0, __shfl_down(m0, off, 64));
    if ((tid & 63) == 0) red[tid >> 6] = m0;
    __syncthreads();
    float bmax = fmaxf(fmaxf(red[0], red[1]), fmaxf(red[2], red[3]));
    float e0 = expf(lg[tid] - bmax);
    float e1 = expf(lg[tid + 256] - bmax);
    float s0 = e0 + e1;
    for (int off = 32; off > 0; off >>= 1) s0 += __shfl_down(s0, off, 64);
    if ((tid & 63) == 0) red[4 + (tid >> 6)] = s0;
    __syncthreads();
    float inv = 1.f / (red[4] + red[5] + red[6] + red[7]);
    out[b * D_ + tid] = e0 * inv;
    out[b * D_ + 256 + tid] = e1 * inv;
}

// ---------------------------------------------------------------------------
extern "C" void kernel_launch(void* const* d_in, const int* in_sizes, int n_in,
                              void* d_out, int out_size, void* d_ws, size_t ws_size,
                              hipStream_t stream)
{
    (void)in_sizes; (void)n_in; (void)out_size; (void)ws_size;

    const int* x = (const int*)d_in[0];
    const int* s = (const int*)d_in[1];
    const float* embed  = (const float*)d_in[2];
    const float* W_ih   = (const float*)d_in[3];
    const float* W_hh   = (const float*)d_in[4];
    const float* b_lstm = (const float*)d_in[5];
    const float* w_y = (const float*)d_in[6];
    const float* w_t = (const float*)d_in[7];
    const float* w_p = (const float*)d_in[8];
    const float* w_x = (const float*)d_in[9];
    const float* w_f = (const float*)d_in[10];
    const float* b_f = (const float*)d_in[11];

    // Workspace (overlaid), peak ~86.5 MB:
    //   [0,64MiB)   phase1: Zx bf16 [16384][2048]
    //               phase2: apre f32 @0, mbuf bf16 @32MiB, Ybuf bf16 @48MiB
    //   [64MiB,+16MiB) Hs bf16 (doubles as the h exchange; sentinel-filled)
    //   @86114304: s_norm, @86245376: rbuf, @86376448: hstar
    char* ws = (char*)d_ws;
    unsigned short* Zx   = (unsigned short*)(ws + 0);
    float*          apre = (float*)(ws + 0);
    unsigned short* mbuf = (unsigned short*)(ws + 33554432);
    unsigned short* Ybuf = (unsigned short*)(ws + 50331648);
    unsigned short* Hs   = (unsigned short*)(ws + 67108864);
    float* s_norm = (float*)(ws + 86114304);
    float* rbuf   = (float*)(ws + 86245376);
    float* hstar  = (float*)(ws + 86376448);

    // 0) sentinel-fill Hs (0xFF bytes -> 0xFFFFFFFF dwords = bf16 NaN pairs)
    hipMemsetAsync(Hs, 0xFF, (size_t)B_ * T_ * D_ * 2, stream);

    // 1) aspect normalization
    aspect_norm<<<dim3(8), dim3(64), 0, stream>>>(s, embed, s_norm);

    // 2) G1: Zx = embed[x] @ W_ih^T + b_lstm  (M=16384, N=2048, K=512)
    gemm_bt<<<dim3(32, 256, 1), dim3(256), 0, stream>>>(
        embed, 1, x, W_ih, nullptr, b_lstm, Zx, nullptr,
        2048, 512, 0L, 0L, 0);

    // 3) recurrence: ONE persistent kernel, 64 blocks x 512 threads
    persistent_lstm<<<dim3(64), dim3(512), 0, stream>>>(
        W_hh, Zx, (unsigned int*)Hs);

    // ---- phase 2: Zx dead; region reused for apre/mbuf/Ybuf ----

    // 4) G2: m[b] = Hs[b] @ circ(s_norm[b])^T
    gemm_bt<<<dim3(8, 4, 64), dim3(256), 0, stream>>>(
        Hs, 0, nullptr, nullptr, s_norm, nullptr, mbuf, nullptr,
        512, 512, (long)(T_ * D_), (long)(T_ * D_), 0);

    // 5) G3: Y = tanh(m @ w_y^T)
    gemm_bt<<<dim3(8, 256, 1), dim3(256), 0, stream>>>(
        mbuf, 0, nullptr, w_y, nullptr, nullptr, Ybuf, nullptr,
        512, 512, 0L, 0L, 1);

    // 6) G4: apre = Y @ w_t^T
    gemm_bt<<<dim3(8, 256, 1), dim3(256), 0, stream>>>(
        Ybuf, 0, nullptr, w_t, nullptr, nullptr, nullptr, apre,
        512, 512, 0L, 0L, 0);

    // 7) softmax over T + r reduction
    attn_r<<<dim3(2, 64), dim3(256), 0, stream>>>(apre, Hs, rbuf);

    // 8) h_star
    hstar_kernel<<<dim3(64), dim3(256), 0, stream>>>(rbuf, Hs, w_p, w_x, hstar);

    // 9) final logits + softmax
    out_kernel<<<dim3(64), dim3(256), 0, stream>>>(hstar, w_f, b_f, (float*)d_out);
}